// Round 2
// baseline (9732.201 us; speedup 1.0000x reference)
//
#include <hip/hip_runtime.h>

// Two-layer tanh RNN, H=32, B=64, T=16384.
// One wave (64 lanes) per batch element; latency-bound sequential scan.
//
// Layouts (per wave):
//  - replication layout: lane m holds h[m&31]   (both 32-lane groups hold a copy)
//  - computed layout:    lane m holds v[r(m)],  r(m) = (m&15) | (m[5]?16:0), dup at m^16
//  - lane m accumulates row r(m) over j in [jb, jb+16), jb = m&16
// Broadcast h[jb+k]: ds_swizzle and=0x10,or=k (bit5-preserving -> per-group correct half).
// Half reduce: ds_swizzle xor=16. computed->replication: ds_bpermute fixed permutation
//  src(m) = (m&15) | ((m&16)<<1).

#define T_LEN 16384
#define B_SZ  64

#define SWZ_F(v, imm) __int_as_float(__builtin_amdgcn_ds_swizzle(__float_as_int(v), (imm)))
#define BC(hv, k)     SWZ_F(hv, (((k) << 5) | 0x10))
#define XOR16(v)      SWZ_F(v, 0x401F)

#define MV_ACC(acc, w, hv, k) acc = fmaf((w)[k], BC(hv, k), acc);

// 16 partial FMAs, alternating accumulators for ILP
#define MATVEC16(accA, accB, w, hv) \
  MV_ACC(accA, w, hv, 0)  MV_ACC(accB, w, hv, 1)  \
  MV_ACC(accA, w, hv, 2)  MV_ACC(accB, w, hv, 3)  \
  MV_ACC(accA, w, hv, 4)  MV_ACC(accB, w, hv, 5)  \
  MV_ACC(accA, w, hv, 6)  MV_ACC(accB, w, hv, 7)  \
  MV_ACC(accA, w, hv, 8)  MV_ACC(accB, w, hv, 9)  \
  MV_ACC(accA, w, hv, 10) MV_ACC(accB, w, hv, 11) \
  MV_ACC(accA, w, hv, 12) MV_ACC(accB, w, hv, 13) \
  MV_ACC(accA, w, hv, 14) MV_ACC(accB, w, hv, 15)

__device__ __forceinline__ float tanh_fast(float v) {
  // tanh(x) = 1 - 2/(exp(2x)+1); native exp saturates correctly at +/-inf.
  float e = __expf(2.0f * v);
  return 1.0f - __fdividef(2.0f, e + 1.0f);
}

__global__ __launch_bounds__(64, 1) void rnn2_kernel(
    const float* __restrict__ x,    const float* __restrict__ hs,
    const float* __restrict__ Wih0, const float* __restrict__ Whh0,
    const float* __restrict__ bih0, const float* __restrict__ bhh0,
    const float* __restrict__ Wih1, const float* __restrict__ Whh1,
    const float* __restrict__ bih1, const float* __restrict__ bhh1,
    const float* __restrict__ Wout, const float* __restrict__ bout,
    float* __restrict__ out)
{
  const int m  = (int)threadIdx.x;
  const int b  = (int)blockIdx.x;
  const int r  = (m & 15) | ((m & 32) ? 16 : 0);  // row this lane accumulates
  const int jb = m & 16;                          // j-half base
  const int i  = m & 31;                          // replication-layout index

  // Per-lane weight rows (one-time load; 16 contiguous floats each)
  float w0[16], wi1[16], wh1[16];
#pragma unroll
  for (int k = 0; k < 16; ++k) {
    w0[k]  = Whh0[r * 32 + jb + k];
    wi1[k] = Wih1[r * 32 + jb + k];
    wh1[k] = Whh1[r * 32 + jb + k];
  }
  const float wih0_r = Wih0[r];
  const float bias0  = bih0[r] + bhh0[r];
  const float bias1  = bih1[r] + bhh1[r];
  const float wout_i = Wout[i];
  const float bo     = bout[0];

  // h_state: [2, B, H]; load in replication layout
  float h0 = hs[b * 32 + i];
  float h1 = hs[2048 + b * 32 + i];

  // computed-layout -> replication-layout bpermute index (bytes)
  const int rep_idx = (((m & 15) | ((m & 16) << 1)) << 2);

  const float* xb  = x + (size_t)b * T_LEN;
  float* outp = out + (size_t)b * T_LEN;             // outs: [B*T], idx b*T+t
  float* hf   = out + (size_t)B_SZ * T_LEN;          // h_final: [2,B,H]

  // Software-pipelined x read: load t+1's value during step t.
  float xcur = xb[0];

  for (int t = 0; t < T_LEN; ++t) {
    int tn = (t + 1 < T_LEN) ? (t + 1) : t;
    float xnext = xb[tn];   // issued early; ~full step of latency hiding
    float xv = xcur;

    float a0 = 0.f, a1 = 0.f;  // layer0: Whh0 @ h0
    float c0 = 0.f, c1 = 0.f;  // layer1: Whh1 @ h1 (independent of h0n -> overlaps)
    MATVEC16(a0, a1, w0,  h0)
    MATVEC16(c0, c1, wh1, h1)

    float s0 = a0 + a1;
    s0 += XOR16(s0);                                   // full row sum, computed layout
    float h0n = tanh_fast(fmaf(xv, wih0_r, bias0) + s0);
    h0n = __int_as_float(__builtin_amdgcn_ds_bpermute(rep_idx, __float_as_int(h0n)));

    MATVEC16(c0, c1, wi1, h0n)                          // + Wih1 @ h0n
    float s1 = c0 + c1;
    s1 += XOR16(s1);                                    // one reduce for both layer-1 matvecs
    float h1n = tanh_fast(bias1 + s1);
    h1n = __int_as_float(__builtin_amdgcn_ds_bpermute(rep_idx, __float_as_int(h1n)));

    // out[t] = dot(h1n, Wout) + bo : butterfly within the 32-lane group (replicated)
    float o = h1n * wout_i;
    o += SWZ_F(o, 0x041F);
    o += SWZ_F(o, 0x081F);
    o += SWZ_F(o, 0x101F);
    o += SWZ_F(o, 0x201F);
    o += XOR16(o);
    if (m == 0) outp[t] = o + bo;   // off the h-critical path; overlaps next step

    h0 = h0n;
    h1 = h1n;
    xcur = xnext;
  }

  // h_final: [2,B,H]
  if (m < 32) hf[b * 32 + i] = h0;
  else        hf[2048 + b * 32 + i] = h1;
}

extern "C" void kernel_launch(void* const* d_in, const int* in_sizes, int n_in,
                              void* d_out, int out_size, void* d_ws, size_t ws_size,
                              hipStream_t stream) {
  rnn2_kernel<<<dim3(B_SZ), dim3(64), 0, stream>>>(
      (const float*)d_in[0],  (const float*)d_in[1],  (const float*)d_in[2],
      (const float*)d_in[3],  (const float*)d_in[4],  (const float*)d_in[5],
      (const float*)d_in[6],  (const float*)d_in[7],  (const float*)d_in[8],
      (const float*)d_in[9],  (const float*)d_in[10], (const float*)d_in[11],
      (float*)d_out);
}

// Round 3
// 9349.139 us; speedup vs baseline: 1.0410x; 1.0410x over previous
//
#include <hip/hip_runtime.h>

// Two-layer tanh RNN, H=32, B=64, T=16384. Latency-bound sequential scan.
//
// Round-3 structure: 32 lanes per batch, 2 batches per wave (grid=32 waves).
// Lane r owns full row r of all three weight matrices (96 VGPRs) and computes
// complete 32-length dots itself -> h lives in natural layout (lane r holds
// h[r]); NO fold/bpermute needed. Broadcasts of h are same-address
// ds_read_b128 from LDS (HW broadcast, conflict-free): 8 reads deliver all 32
// values to every lane. Per-wave DS ops/step: 24 reads + 2 writes + 5 output
// swizzles + 1 x-bpermute. DS pipe is in-order per wave -> write h0n then
// read-back needs no barrier (block = 1 wave).

#define T_LEN 16384
#define B_SZ  64

#define SWZ_F(v, imm) __int_as_float(__builtin_amdgcn_ds_swizzle(__float_as_int(v), (imm)))

__device__ __forceinline__ float tanh_fast(float v) {
  // tanh(x) = 1 - 2/(exp(2x)+1); saturates correctly at +/-inf.
  float e = __expf(2.0f * v);
  return 1.0f - __fdividef(2.0f, e + 1.0f);
}

__global__ __launch_bounds__(64, 1) void rnn2_kernel(
    const float* __restrict__ x,    const float* __restrict__ hs,
    const float* __restrict__ Wih0, const float* __restrict__ Whh0,
    const float* __restrict__ bih0, const float* __restrict__ bhh0,
    const float* __restrict__ Wih1, const float* __restrict__ Whh1,
    const float* __restrict__ bih1, const float* __restrict__ bhh1,
    const float* __restrict__ Wout, const float* __restrict__ bout,
    float* __restrict__ out)
{
  // LDS: per half, h0 slot and h1 slot, padded to 36 floats (144 B) so the
  // two halves' regions sit on different banks (write = 2-way alias, free).
  __shared__ __align__(16) float lds[144];

  const int m    = (int)threadIdx.x;
  const int half = m >> 5;
  const int r    = m & 31;
  const int b    = (int)blockIdx.x * 2 + half;

  // Per-lane weight rows: row r of Whh0, Wih1, Whh1 (96 VGPRs).
  float w0[32], wi1[32], wh1[32];
#pragma unroll
  for (int k = 0; k < 8; ++k) {
    float4 q0 = ((const float4*)(Whh0 + r * 32))[k];
    w0[4*k] = q0.x; w0[4*k+1] = q0.y; w0[4*k+2] = q0.z; w0[4*k+3] = q0.w;
    float4 q1 = ((const float4*)(Wih1 + r * 32))[k];
    wi1[4*k] = q1.x; wi1[4*k+1] = q1.y; wi1[4*k+2] = q1.z; wi1[4*k+3] = q1.w;
    float4 q2 = ((const float4*)(Whh1 + r * 32))[k];
    wh1[4*k] = q2.x; wh1[4*k+1] = q2.y; wh1[4*k+2] = q2.z; wh1[4*k+3] = q2.w;
  }
  const float wih0_r = Wih0[r];
  const float bias0  = bih0[r] + bhh0[r];
  const float bias1  = bih1[r] + bhh1[r];
  const float wout_r = Wout[r];
  const float bo     = bout[0];

  // h_state [2,B,H] -> natural layout
  float h0 = hs[b * 32 + r];
  float h1 = hs[2048 + b * 32 + r];

  const int h0off = half * 36;
  const int h1off = 72 + half * 36;
  lds[h0off + r] = h0;
  lds[h1off + r] = h1;
  const float4* p0 = (const float4*)(lds + h0off);
  const float4* p1 = (const float4*)(lds + h1off);

  const float* xb   = x + (size_t)b * T_LEN;
  float*       outp = out + (size_t)b * T_LEN;       // outs[b*T + t]
  float*       hf   = out + (size_t)B_SZ * T_LEN;    // h_final [2,B,H]

  const int xsel_base = (m & 32) << 2;  // bpermute byte base (per-half source group)

  // x: one coalesced load per 32 steps, per-step broadcast via ds_bpermute.
  float xchunk = xb[r];

  for (int t0 = 0; t0 < T_LEN; t0 += 32) {
    int nid = t0 + 32 + r;
    if (nid >= T_LEN) nid = T_LEN - 1;
    float xnext = xb[nid];  // prefetch next window (32 steps of slack)

    for (int t2 = 0; t2 < 32; ++t2) {
      float xv = __int_as_float(__builtin_amdgcn_ds_bpermute(
          xsel_base | (t2 << 2), __float_as_int(xchunk)));

      // Layer 0: a = Whh0 @ h0 (h0 slot holds last step's h0n)
      float a0 = 0.f, a1 = 0.f, a2 = 0.f, a3 = 0.f;
#pragma unroll
      for (int k = 0; k < 8; ++k) {
        float4 hv = p0[k];
        a0 = fmaf(w0[4*k],   hv.x, a0);
        a1 = fmaf(w0[4*k+1], hv.y, a1);
        a2 = fmaf(w0[4*k+2], hv.z, a2);
        a3 = fmaf(w0[4*k+3], hv.w, a3);
      }
      float pre0 = fmaf(xv, wih0_r, bias0);
      float h0n  = tanh_fast(pre0 + ((a0 + a1) + (a2 + a3)));
      lds[h0off + r] = h0n;

      // Layer 1 part A: c = Whh1 @ h1 — placed AFTER the h0n write so these
      // 32 FMAs fill the write->read-back DS turnaround latency.
      float c0 = 0.f, c1 = 0.f, c2 = 0.f, c3 = 0.f;
#pragma unroll
      for (int k = 0; k < 8; ++k) {
        float4 hv = p1[k];
        c0 = fmaf(wh1[4*k],   hv.x, c0);
        c1 = fmaf(wh1[4*k+1], hv.y, c1);
        c2 = fmaf(wh1[4*k+2], hv.z, c2);
        c3 = fmaf(wh1[4*k+3], hv.w, c3);
      }
      // Layer 1 part B: + Wih1 @ h0n (read back; in-order DS pipe)
#pragma unroll
      for (int k = 0; k < 8; ++k) {
        float4 hv = p0[k];
        c0 = fmaf(wi1[4*k],   hv.x, c0);
        c1 = fmaf(wi1[4*k+1], hv.y, c1);
        c2 = fmaf(wi1[4*k+2], hv.z, c2);
        c3 = fmaf(wi1[4*k+3], hv.w, c3);
      }
      float h1n = tanh_fast(bias1 + ((c0 + c1) + (c2 + c3)));
      lds[h1off + r] = h1n;

      // out[t] = dot(h1n, Wout) + bo : 5-swizzle butterfly within 32-group
      float o = h1n * wout_r;
      o += SWZ_F(o, 0x041F);
      o += SWZ_F(o, 0x081F);
      o += SWZ_F(o, 0x101F);
      o += SWZ_F(o, 0x201F);
      o += SWZ_F(o, 0x401F);
      if (r == 0) outp[t0 + t2] = o + bo;

      h0 = h0n;
      h1 = h1n;
    }
    xchunk = xnext;
  }

  // h_final [2,B,H]
  hf[b * 32 + r]        = h0;
  hf[2048 + b * 32 + r] = h1;
}

extern "C" void kernel_launch(void* const* d_in, const int* in_sizes, int n_in,
                              void* d_out, int out_size, void* d_ws, size_t ws_size,
                              hipStream_t stream) {
  rnn2_kernel<<<dim3(B_SZ / 2), dim3(64), 0, stream>>>(
      (const float*)d_in[0],  (const float*)d_in[1],  (const float*)d_in[2],
      (const float*)d_in[3],  (const float*)d_in[4],  (const float*)d_in[5],
      (const float*)d_in[6],  (const float*)d_in[7],  (const float*)d_in[8],
      (const float*)d_in[9],  (const float*)d_in[10], (const float*)d_in[11],
      (float*)d_out);
}

// Round 5
// 6610.275 us; speedup vs baseline: 1.4723x; 1.4143x over previous
//
#include <hip/hip_runtime.h>

// Two-layer tanh RNN, H=32, B=64, T=16384. Latency-bound sequential scan.
//
// Round-5 structure (round-4 fixed): one wave per batch (lanes 32-63 duplicate
// lanes 0-31). Lane r owns full row r of Whh0/Wih1/Whh1 (96 VGPRs). Broadcast
// of h is v_readlane -> wave-uniform SGPR consumed directly as the SGPR
// operand of v_fma_f32: ZERO DS-pipe ops anywhere (round-3 was DS-round-trip
// bound at ~1370 cyc/step). h0n's 32 readlanes are cached (used by L1B now
// and L0 next step); h1's are inlined (single use). Output dot is a 5-op DPP
// butterfly (VALU pipe) + readlane(31), buffered via cndmask select, stored
// coalesced once per 32 steps.
//
// Compile fixes vs round 4: update_dpp args must be ICE -> template params;
// __builtin_amdgcn_writelane undeclared -> (m==t2) ? s : obuf select.

#define T_LEN 16384
#define B_SZ  64

__device__ __forceinline__ float rl(float v, int lane) {
  return __int_as_float(__builtin_amdgcn_readlane(__float_as_int(v), lane));
}

template <int CTRL, int RMASK>
__device__ __forceinline__ float dpp_add(float v) {
  int t = __builtin_amdgcn_update_dpp(0, __float_as_int(v), CTRL, RMASK, 0xf, true);
  return v + __int_as_float(t);
}

__device__ __forceinline__ float tanh_fast(float v) {
  // tanh(x) = 1 - 2/(exp(2x)+1); saturates correctly at +/-inf.
  float e = __expf(2.0f * v);
  return 1.0f - __fdividef(2.0f, e + 1.0f);
}

__global__ __launch_bounds__(64, 1) void rnn2_kernel(
    const float* __restrict__ x,    const float* __restrict__ hs,
    const float* __restrict__ Wih0, const float* __restrict__ Whh0,
    const float* __restrict__ bih0, const float* __restrict__ bhh0,
    const float* __restrict__ Wih1, const float* __restrict__ Whh1,
    const float* __restrict__ bih1, const float* __restrict__ bhh1,
    const float* __restrict__ Wout, const float* __restrict__ bout,
    float* __restrict__ out)
{
  const int m = (int)threadIdx.x;
  const int r = m & 31;            // row this lane owns (upper half duplicates)
  const int b = (int)blockIdx.x;   // one batch per wave

  // Full weight rows in VGPRs (96 VGPRs).
  float w0[32], wi1[32], wh1[32];
#pragma unroll
  for (int k = 0; k < 8; ++k) {
    float4 q0 = ((const float4*)(Whh0 + r * 32))[k];
    w0[4*k] = q0.x;  w0[4*k+1] = q0.y;  w0[4*k+2] = q0.z;  w0[4*k+3] = q0.w;
    float4 q1 = ((const float4*)(Wih1 + r * 32))[k];
    wi1[4*k] = q1.x; wi1[4*k+1] = q1.y; wi1[4*k+2] = q1.z; wi1[4*k+3] = q1.w;
    float4 q2 = ((const float4*)(Whh1 + r * 32))[k];
    wh1[4*k] = q2.x; wh1[4*k+1] = q2.y; wh1[4*k+2] = q2.z; wh1[4*k+3] = q2.w;
  }
  const float wih0_r = Wih0[r];
  const float bias0  = bih0[r] + bhh0[r];
  const float bias1  = bih1[r] + bhh1[r];
  const float wout_r = Wout[r];
  const float bo     = bout[0];

  float h0 = hs[b * 32 + r];
  float h1 = hs[2048 + b * 32 + r];

  // Cached wave-uniform broadcast of h0 (refreshed from h0n each step).
  float sh0[32];
#pragma unroll
  for (int j = 0; j < 32; ++j) sh0[j] = rl(h0, j);

  const float* xb   = x + (size_t)b * T_LEN;
  float*       outp = out + (size_t)b * T_LEN;       // outs[b*T + t]
  float*       hf   = out + (size_t)B_SZ * T_LEN;    // h_final [2,B,H]

  float xchunk = xb[r];   // lanes 0..31 hold x[t0 + r]
  float obuf   = 0.f;

  for (int t0 = 0; t0 < T_LEN; t0 += 32) {
    int nid = t0 + 32 + r;
    if (nid >= T_LEN) nid = T_LEN - 1;
    float xnext = xb[nid];  // prefetch next window (32 steps of slack)

#pragma unroll 2
    for (int t2 = 0; t2 < 32; ++t2) {
      float xv = rl(xchunk, t2);

      // L0: Whh0 @ h0 (cached sh0)  and  L1A: Whh1 @ h1 (inline rl, single
      // use) — independent chains, interleaved for ILP.
      float a0 = 0.f, a1 = 0.f, a2 = 0.f, a3 = 0.f;
      float c0 = 0.f, c1 = 0.f, c2 = 0.f, c3 = 0.f;
#pragma unroll
      for (int k = 0; k < 8; ++k) {
        a0 = fmaf(w0[4*k],    sh0[4*k],         a0);
        a1 = fmaf(w0[4*k+1],  sh0[4*k+1],       a1);
        a2 = fmaf(w0[4*k+2],  sh0[4*k+2],       a2);
        a3 = fmaf(w0[4*k+3],  sh0[4*k+3],       a3);
        c0 = fmaf(wh1[4*k],   rl(h1, 4*k),      c0);
        c1 = fmaf(wh1[4*k+1], rl(h1, 4*k+1),    c1);
        c2 = fmaf(wh1[4*k+2], rl(h1, 4*k+2),    c2);
        c3 = fmaf(wh1[4*k+3], rl(h1, 4*k+3),    c3);
      }
      float h0n = tanh_fast(fmaf(xv, wih0_r, bias0) + ((a0 + a1) + (a2 + a3)));

      // Refresh cached broadcast (serves L1B now and L0 next step).
#pragma unroll
      for (int j = 0; j < 32; ++j) sh0[j] = rl(h0n, j);

      // L1B: + Wih1 @ h0n
#pragma unroll
      for (int k = 0; k < 8; ++k) {
        c0 = fmaf(wi1[4*k],   sh0[4*k],   c0);
        c1 = fmaf(wi1[4*k+1], sh0[4*k+1], c1);
        c2 = fmaf(wi1[4*k+2], sh0[4*k+2], c2);
        c3 = fmaf(wi1[4*k+3], sh0[4*k+3], c3);
      }
      float h1n = tanh_fast(bias1 + ((c0 + c1) + (c2 + c3)));

      // out[t] = dot(h1n, Wout) + bo — DPP butterfly over lanes 0..31:
      // row_shr 1/2/4/8 then row_bcast15 into rows 1,3; lane 31 holds the
      // 32-lane sum. Pure VALU pipe.
      float o = h1n * wout_r;
      o = dpp_add<0x111, 0xf>(o);   // row_shr:1
      o = dpp_add<0x112, 0xf>(o);   // row_shr:2
      o = dpp_add<0x114, 0xf>(o);   // row_shr:4
      o = dpp_add<0x118, 0xf>(o);   // row_shr:8
      o = dpp_add<0x142, 0xa>(o);   // row_bcast:15 into rows 1,3
      float so = rl(o, 31);
      obuf = (m == t2) ? so : obuf; // lane t2 keeps out[t0+t2]

      h0 = h0n;
      h1 = h1n;
    }

    if (m < 32) outp[t0 + r] = obuf + bo;   // coalesced 32-float store/window
    xchunk = xnext;
  }

  // h_final [2,B,H]
  if (m < 32) {
    hf[b * 32 + r]        = h0;
    hf[2048 + b * 32 + r] = h1;
  }
}

extern "C" void kernel_launch(void* const* d_in, const int* in_sizes, int n_in,
                              void* d_out, int out_size, void* d_ws, size_t ws_size,
                              hipStream_t stream) {
  rnn2_kernel<<<dim3(B_SZ), dim3(64), 0, stream>>>(
      (const float*)d_in[0],  (const float*)d_in[1],  (const float*)d_in[2],
      (const float*)d_in[3],  (const float*)d_in[4],  (const float*)d_in[5],
      (const float*)d_in[6],  (const float*)d_in[7],  (const float*)d_in[8],
      (const float*)d_in[9],  (const float*)d_in[10], (const float*)d_in[11],
      (float*)d_out);
}